// Round 1
// baseline (1085.658 us; speedup 1.0000x reference)
//
#include <hip/hip_runtime.h>

// TT/MPO matvec: out[b,o1,o2,o3] = sum_{i1,i2,i3,k1,k2}
//   core0[0,o1,i1,k1] * core1[k1,o2,i2,k2] * core2[k2,o3,i3,0] * v[b,i1,i2,i3]
//
// Strategy (round 1, fp32 correctness-first):
//   block = one batch element b; loop o1 (16 iters):
//     G1: T1[k1,i2,i3]   = sum_i1 core0[o1,i1,k1] * v[b,i1,i2,i3]     (LDS, padded)
//     G2: T2[(o2,k2),i3] = sum_{k1,i2} core1[k1,o2,i2,k2] * T1[...]   (4x4 reg tile)
//     G3: out[b,o1,o2,o3]= sum_{k2,i3} core2[k2,o3,i3] * T2[(o2,k2),i3]

constexpr int T1_LD = 20;  // pad 16 -> 20 floats: breaks power-of-2 bank stride
constexpr int T2_LD = 20;

__global__ __launch_bounds__(256) void tt_matvec_f32(
    const float* __restrict__ vg,    // (B,16,16,16)
    const float* __restrict__ c0g,   // (1,16,16,16)  [o1][i1][k1]
    const float* __restrict__ c1g,   // (16,16,16,16) [k1][o2][i2][k2]
    const float* __restrict__ c2g,   // (16,16,16,1)  [k2][o3][i3]
    float* __restrict__ outg)        // (B,16,16,16)  [b][o1][o2][o3]
{
    const int b = blockIdx.x;
    const int t = threadIdx.x;

    __shared__ float T1p[256 * T1_LD];  // [kk = k1*16+i2][i3]
    __shared__ float T2p[256 * T2_LD];  // [row = o2*16+k2][i3]

    // G1 mapping: thread = (k1, i2)
    const int k1 = t >> 4, i2 = t & 15;
    // G2 mapping: thread = (row-group rg -> 4 rows, col-group cg -> 4 i3)
    const int rg = t >> 2, cg = t & 3;
    const int o2g = rg >> 2;            // rows rg*4 .. rg*4+3 = o2g*16 + k2b + j
    const int k2b = (rg & 3) << 2;
    // G3 mapping: thread = (o2, o3)
    const int o2c = t >> 4, o3 = t & 15;

    const float* vb = vg + (size_t)b * 4096;
    float* ob = outg + (size_t)b * 4096;

    for (int o1 = 0; o1 < 16; ++o1) {
        __syncthreads();  // prev iter's G2/G3 done reading T1p/T2p

        // ---------------- G1: T1[k1][i2][i3] ----------------
        float c0r[16];
        #pragma unroll
        for (int i1 = 0; i1 < 16; ++i1)
            c0r[i1] = c0g[o1 * 256 + i1 * 16 + k1];

        float a1[16];
        #pragma unroll
        for (int j = 0; j < 16; ++j) a1[j] = 0.f;

        #pragma unroll 4
        for (int i1 = 0; i1 < 16; ++i1) {
            const float4* vp = (const float4*)(vb + i1 * 256 + i2 * 16);
            const float c = c0r[i1];
            #pragma unroll
            for (int q = 0; q < 4; ++q) {
                float4 v4 = vp[q];
                a1[q * 4 + 0] += c * v4.x;
                a1[q * 4 + 1] += c * v4.y;
                a1[q * 4 + 2] += c * v4.z;
                a1[q * 4 + 3] += c * v4.w;
            }
        }
        #pragma unroll
        for (int q = 0; q < 4; ++q)
            *(float4*)&T1p[t * T1_LD + q * 4] =
                make_float4(a1[q * 4 + 0], a1[q * 4 + 1], a1[q * 4 + 2], a1[q * 4 + 3]);

        __syncthreads();

        // ---------------- G2: T2[(o2,k2)][i3] ----------------
        float acc[4][4];
        #pragma unroll
        for (int j = 0; j < 4; ++j)
            #pragma unroll
            for (int i = 0; i < 4; ++i) acc[j][i] = 0.f;

        for (int k1q = 0; k1q < 16; ++k1q) {
            const float* arow = c1g + k1q * 4096 + o2g * 256 + k2b;      // [i2q*16 + j]
            const float* brow = &T1p[(k1q * 16) * T1_LD + (cg << 2)];    // [i2q*T1_LD + i]
            #pragma unroll
            for (int i2q = 0; i2q < 16; ++i2q) {
                float4 av = *(const float4*)(arow + i2q * 16);    // rows j=0..3 (k2 dir)
                float4 bv = *(const float4*)(brow + i2q * T1_LD); // cols i=0..3 (i3 dir)
                acc[0][0] += av.x * bv.x; acc[0][1] += av.x * bv.y;
                acc[0][2] += av.x * bv.z; acc[0][3] += av.x * bv.w;
                acc[1][0] += av.y * bv.x; acc[1][1] += av.y * bv.y;
                acc[1][2] += av.y * bv.z; acc[1][3] += av.y * bv.w;
                acc[2][0] += av.z * bv.x; acc[2][1] += av.z * bv.y;
                acc[2][2] += av.z * bv.z; acc[2][3] += av.z * bv.w;
                acc[3][0] += av.w * bv.x; acc[3][1] += av.w * bv.y;
                acc[3][2] += av.w * bv.z; acc[3][3] += av.w * bv.w;
            }
        }
        #pragma unroll
        for (int j = 0; j < 4; ++j)
            *(float4*)&T2p[(o2g * 16 + k2b + j) * T2_LD + (cg << 2)] =
                make_float4(acc[j][0], acc[j][1], acc[j][2], acc[j][3]);

        __syncthreads();

        // ---------------- G3: out[b,o1,o2,o3] ----------------
        float acc3 = 0.f;
        #pragma unroll
        for (int k2 = 0; k2 < 16; ++k2) {
            const float* t2r = &T2p[(o2c * 16 + k2) * T2_LD];
            const float* c2r = c2g + k2 * 256 + o3 * 16;
            #pragma unroll
            for (int q = 0; q < 4; ++q) {
                float4 tv = *(const float4*)(t2r + q * 4);
                float4 cv = *(const float4*)(c2r + q * 4);
                acc3 += tv.x * cv.x + tv.y * cv.y + tv.z * cv.z + tv.w * cv.w;
            }
        }
        ob[o1 * 256 + t] = acc3;
    }
}

extern "C" void kernel_launch(void* const* d_in, const int* in_sizes, int n_in,
                              void* d_out, int out_size, void* d_ws, size_t ws_size,
                              hipStream_t stream) {
    const float* vg  = (const float*)d_in[0];
    const float* c0g = (const float*)d_in[1];
    const float* c1g = (const float*)d_in[2];
    const float* c2g = (const float*)d_in[3];
    float* outg = (float*)d_out;

    const int B = in_sizes[0] / 4096;  // 1024
    tt_matvec_f32<<<dim3(B), dim3(256), 0, stream>>>(vg, c0g, c1g, c2g, outg);
}

// Round 2
// 438.252 us; speedup vs baseline: 2.4772x; 2.4772x over previous
//
#include <hip/hip_runtime.h>

// TT/MPO matvec on MFMA (bf16 in / f32 accum):
//   S1: T1'[(o1,k1),(i2,i3)] = c0m[(o1,k1),i1] x v[i1,(i2,i3)]      (K=16 pad 32)
//   S2: T2[(o2,k2),(o1,i3)]  = c1m[(o2,k2),(k1,i2)] x T1[(k1,i2),(o1,i3)]
//   S3: out[b,o1,o2,o3]      = sum_(k2,i3) c2m[o3,(k2,i3)] x T2  (batched o1)
// Block = one b, 4 waves, o1 chunked by 4 (nc loop). LDS: T1 32K + T2 32K = 64K -> 2 blocks/CU.
// c0/c1/c2 pre-repacked to A-fragment layout (bf16) in d_ws by tt_repack.

typedef short bf16x8 __attribute__((ext_vector_type(8)));
typedef float f32x4 __attribute__((ext_vector_type(4)));

#define WS_A1_OFF 0        // c1 frags: 16 mt x 8 ks x 64 lanes x 16B = 131072
#define WS_A0_OFF 131072   // c0 frags: 16 mt x 64 lanes x 16B      = 16384
#define WS_A2_OFF 147456   // c2 frags:  8 ks x 64 lanes x 16B      = 8192
#define WS_NEEDED 155648

__device__ __forceinline__ unsigned short f2bf(float f) {
    union { float f; unsigned int u; } x; x.f = f;
    unsigned int u = x.u;
    u += 0x7fffu + ((u >> 16) & 1u);   // RNE
    return (unsigned short)(u >> 16);
}

// ---------------- repack: c0/c1/c2 -> bf16 A-fragment layout in ws ----------------
__global__ void tt_repack(const float* __restrict__ c0,
                          const float* __restrict__ c1,
                          const float* __restrict__ c2,
                          unsigned short* __restrict__ ws) {
    int idx = blockIdx.x * 256 + threadIdx.x;
    if (idx < 8192) {                      // A1 (c1): frag (mt, ks, lane)
        int mt = idx >> 9, ks = (idx >> 6) & 7, l = idx & 63;
        int o2 = mt, k2 = l & 15;
        unsigned short* dst = ws + ((size_t)(mt * 8 + ks) * 64 + l) * 8;
        #pragma unroll
        for (int j = 0; j < 8; ++j) {
            int k = ks * 32 + ((l >> 4) * 8) + j;      // (k1,i2)
            dst[j] = f2bf(c1[(k >> 4) * 4096 + o2 * 256 + (k & 15) * 16 + k2]);
        }
    } else if (idx < 9216) {               // A0 (c0): frag (mt, lane), K=16 padded
        int t = idx - 8192;
        int mt = t >> 6, l = t & 63;
        unsigned short* dst = ws + WS_A0_OFF / 2 + ((size_t)mt * 64 + l) * 8;
        #pragma unroll
        for (int j = 0; j < 8; ++j) {
            int k = ((l >> 4) * 8) + j;                // i1 (or pad)
            float v = (l < 32) ? c0[mt * 256 + k * 16 + (l & 15)] : 0.f;
            dst[j] = f2bf(v);
        }
    } else if (idx < 9728) {               // A2 (c2): frag (ks, lane)
        int t = idx - 9216;
        int ks = t >> 6, l = t & 63;
        unsigned short* dst = ws + WS_A2_OFF / 2 + ((size_t)ks * 64 + l) * 8;
        #pragma unroll
        for (int j = 0; j < 8; ++j) {
            int k = ks * 32 + ((l >> 4) * 8) + j;      // (k2,i3)
            dst[j] = f2bf(c2[(k >> 4) * 256 + (l & 15) * 16 + (k & 15)]);
        }
    }
}

// ---------------- main kernel ----------------
template <bool PACKED>
__global__ __launch_bounds__(256, 2) void tt_main(
    const float* __restrict__ vg, const float* __restrict__ c0,
    const float* __restrict__ c1, const float* __restrict__ c2,
    const unsigned short* __restrict__ ws, float* __restrict__ outg)
{
    __shared__ unsigned short T1[16384]; // [n_local=(o1l,i3) 64][k=(k1,i2) 256], byte ^ ((n&7)<<4)
    __shared__ unsigned short T2[16384]; // [o2 16][k2 16][o1l 4][i3 16],        byte ^ ((o2&7)<<4)

    const int b   = blockIdx.x;
    const int t   = threadIdx.x;
    const int w   = t >> 6;        // wave 0..3
    const int l   = t & 63;
    const int l15 = l & 15;
    const int lg  = l >> 4;

    // ---- preload: v B-frags (per-b) and held c1 A-frags ----
    bf16x8 fb0[4];
    {
        const float* vb = vg + (size_t)b * 4096;
        #pragma unroll
        for (int nt = 0; nt < 4; ++nt) {
            bf16x8 f = {0, 0, 0, 0, 0, 0, 0, 0};
            if (l < 32) {
                int i2 = 4 * w + nt;
                const float* p = vb + (lg * 8) * 256 + i2 * 16 + l15;
                #pragma unroll
                for (int j = 0; j < 8; ++j) f[j] = (short)f2bf(p[j * 256]);
            }
            fb0[nt] = f;
        }
    }
    bf16x8 fa1[4][8];   // wave's 64 rows (o2 = 4w..4w+3) x K=256 of c1
    if constexpr (PACKED) {
        #pragma unroll
        for (int rt = 0; rt < 4; ++rt)
            #pragma unroll
            for (int ks = 0; ks < 8; ++ks)
                fa1[rt][ks] = *(const bf16x8*)(ws + ((size_t)((w * 4 + rt) * 8 + ks) * 64 + l) * 8);
    } else {
        for (int rt = 0; rt < 4; ++rt)
            for (int ks = 0; ks < 8; ++ks) {
                int o2 = w * 4 + rt, k2 = l15;
                bf16x8 f;
                for (int j = 0; j < 8; ++j) {
                    int k = ks * 32 + lg * 8 + j;
                    f[j] = (short)f2bf(c1[(k >> 4) * 4096 + o2 * 256 + (k & 15) * 16 + k2]);
                }
                fa1[rt][ks] = f;
            }
    }

    for (int nc = 0; nc < 4; ++nc) {       // o1 chunk: o1 = nc*4 .. nc*4+3
        // ---------- S1: T1 for this chunk's 4 o1 values ----------
        #pragma unroll
        for (int mtl = 0; mtl < 4; ++mtl) {
            const int mt = nc * 4 + mtl;   // = o1
            bf16x8 fa0;
            if constexpr (PACKED) {
                fa0 = *(const bf16x8*)(ws + WS_A0_OFF / 2 + ((size_t)mt * 64 + l) * 8);
            } else {
                bf16x8 f = {0, 0, 0, 0, 0, 0, 0, 0};
                if (l < 32) {
                    #pragma unroll
                    for (int j = 0; j < 8; ++j)
                        f[j] = (short)f2bf(c0[mt * 256 + (lg * 8 + j) * 16 + l15]);
                }
                fa0 = f;
            }
            #pragma unroll
            for (int nt = 0; nt < 4; ++nt) {
                f32x4 z = {0.f, 0.f, 0.f, 0.f};
                f32x4 d = __builtin_amdgcn_mfma_f32_16x16x32_bf16(fa0, fb0[nt], z, 0, 0, 0);
                // D: row -> (o1=mt, k1 = lg*4+r); col -> (i2 = 4w+nt, i3 = l15)
                const int i2 = 4 * w + nt;
                const int nl = mtl * 16 + l15;             // T1 row (o1l, i3)
                #pragma unroll
                for (int r = 0; r < 4; ++r) {
                    int kk = (lg * 4 + r) * 16 + i2;       // (k1, i2)
                    int byte = (nl * 512 + kk * 2) ^ ((nl & 7) << 4);
                    *(unsigned short*)((char*)T1 + byte) = f2bf(d[r]);
                }
            }
        }
        __syncthreads();

        // ---------- S2: T2 = c1m x T1 (M split by wave: o2 = 4w..4w+3) ----------
        {
            f32x4 acc[4][4];
            #pragma unroll
            for (int rt = 0; rt < 4; ++rt)
                #pragma unroll
                for (int nt = 0; nt < 4; ++nt) acc[rt][nt] = (f32x4){0.f, 0.f, 0.f, 0.f};

            #pragma unroll
            for (int nt = 0; nt < 4; ++nt) {
                const int nl = nt * 16 + l15;
                #pragma unroll
                for (int ks = 0; ks < 8; ++ks) {
                    int byte = (nl * 512 + (ks * 32 + lg * 8) * 2) ^ ((nl & 7) << 4);
                    bf16x8 fb = *(const bf16x8*)((char*)T1 + byte);
                    #pragma unroll
                    for (int rt = 0; rt < 4; ++rt)
                        acc[rt][nt] = __builtin_amdgcn_mfma_f32_16x16x32_bf16(
                            fa1[rt][ks], fb, acc[rt][nt], 0, 0, 0);
                }
            }
            // flush to T2: row -> (o2 = 4w+rt, k2 = lg*4+r); col -> (o1l = nt, i3 = l15)
            #pragma unroll
            for (int rt = 0; rt < 4; ++rt) {
                const int o2 = w * 4 + rt;
                #pragma unroll
                for (int nt = 0; nt < 4; ++nt) {
                    #pragma unroll
                    for (int r = 0; r < 4; ++r) {
                        int k2 = lg * 4 + r;
                        int byte = ((o2 * 16 + k2) * 128 + nt * 32 + l15 * 2) ^ ((o2 & 7) << 4);
                        *(unsigned short*)((char*)T2 + byte) = f2bf(acc[rt][nt][r]);
                    }
                }
            }
        }
        __syncthreads();

        // ---------- S3: out[b, o1, :, :] = c2m x T2 (batched over 4 o1) ----------
        {
            bf16x8 fa2[8];
            if constexpr (PACKED) {
                #pragma unroll
                for (int ks = 0; ks < 8; ++ks)
                    fa2[ks] = *(const bf16x8*)(ws + WS_A2_OFF / 2 + ((size_t)ks * 64 + l) * 8);
            } else {
                for (int ks = 0; ks < 8; ++ks) {
                    bf16x8 f;
                    for (int j = 0; j < 8; ++j) {
                        int k = ks * 32 + lg * 8 + j;
                        f[j] = (short)f2bf(c2[(k >> 4) * 256 + l15 * 16 + (k & 15)]);
                    }
                    fa2[ks] = f;
                }
            }
            float* ob = outg + (size_t)b * 4096;
            #pragma unroll
            for (int o1l = 0; o1l < 4; ++o1l) {
                f32x4 acc3 = {0.f, 0.f, 0.f, 0.f};
                #pragma unroll
                for (int ks = 0; ks < 8; ++ks) {
                    // B: n = o2 = l15; k = ks*32 + lg*8 + j -> (k2, i3)
                    int k2  = ks * 2 + (lg >> 1);
                    int i3b = (lg & 1) * 8;
                    int byte = ((l15 * 16 + k2) * 128 + o1l * 32 + i3b * 2) ^ ((l15 & 7) << 4);
                    bf16x8 fb = *(const bf16x8*)((char*)T2 + byte);
                    acc3 = __builtin_amdgcn_mfma_f32_16x16x32_bf16(fa2[ks], fb, acc3, 0, 0, 0);
                }
                // D: row = o3 = lg*4+r, col = o2 = l15
                *(f32x4*)(ob + (nc * 4 + o1l) * 256 + l15 * 16 + lg * 4) = acc3;
            }
        }
        __syncthreads();
    }
}

extern "C" void kernel_launch(void* const* d_in, const int* in_sizes, int n_in,
                              void* d_out, int out_size, void* d_ws, size_t ws_size,
                              hipStream_t stream) {
    const float* vg  = (const float*)d_in[0];
    const float* c0g = (const float*)d_in[1];
    const float* c1g = (const float*)d_in[2];
    const float* c2g = (const float*)d_in[3];
    float* outg = (float*)d_out;

    const int B = in_sizes[0] / 4096;
    const bool packed = (ws_size >= (size_t)WS_NEEDED) && (d_ws != nullptr);

    if (packed) {
        tt_repack<<<dim3(38), dim3(256), 0, stream>>>(c0g, c1g, c2g, (unsigned short*)d_ws);
        tt_main<true><<<dim3(B), dim3(256), 0, stream>>>(
            vg, c0g, c1g, c2g, (const unsigned short*)d_ws, outg);
    } else {
        tt_main<false><<<dim3(B), dim3(256), 0, stream>>>(
            vg, c0g, c1g, c2g, nullptr, outg);
    }
}

// Round 4
// 54.290 us; speedup vs baseline: 19.9973x; 8.0724x over previous
//
#include <hip/hip_runtime.h>

// TT/MPO matvec on MFMA (bf16 in / f32 accum), round 4.
//   S1: T1[(o1l,i3)][(i2,k1)] = c0m x v        (per o1, K=16 pad 32)
//   S2: T2[(o1l,o2)][(i3,k2)] = c1m x T1       (M tiled by o2, K=(i2,k1))
//   S3: out[b,o1,o2,o3]       = c2m x T2       (wave w owns o1l=w)
// Block = one b, 4 waves, o1 chunked by 4. LDS 64 KB -> 2 blocks/CU.
// c1 A-frags STREAMED from L2-resident ws each ks step (round-2 lesson: holding
// them spilled 520 B/thread to scratch = 560 MB HBM traffic).
// Round-3 lesson: v_cvt_pk_bf16_f32 inline asm produced NaN -> software pack.

typedef short bf16x8 __attribute__((ext_vector_type(8)));
typedef float f32x4 __attribute__((ext_vector_type(4)));

#define WS_A1_OFF 0        // c1 frags: 16 o2 x 8 ks x 64 lanes x 16B = 131072 B
#define WS_A0_OFF 131072   // c0 frags: 16 o1 x 64 lanes x 16B       = 16384 B
#define WS_A2_OFF 147456   // c2 frags:  8 ks x 64 lanes x 16B       = 8192 B
#define WS_NEEDED 155648

__device__ __forceinline__ unsigned short f2bf(float f) {
    union { float f; unsigned int u; } x; x.f = f;
    unsigned int u = x.u;
    u += 0x7fffu + ((u >> 16) & 1u);   // RNE
    return (unsigned short)(u >> 16);
}

__device__ __forceinline__ unsigned int pk_bf16(float lo, float hi) {
    // software pack (round 3's v_cvt_pk_bf16_f32 asm gave NaN): lo -> [15:0], hi -> [31:16]
    return (unsigned int)f2bf(lo) | ((unsigned int)f2bf(hi) << 16);
}

// ---------------- repack: c0/c1/c2 -> bf16 A-fragment layout in ws ----------------
// k-dim orderings: S2 kappa=(i2,k1): i2=k>>4, k1=k&15.  S3 kappa2=(i3,k2): i3=k>>4, k2=k&15.
__global__ void tt_repack(const float* __restrict__ c0,
                          const float* __restrict__ c1,
                          const float* __restrict__ c2,
                          unsigned short* __restrict__ ws) {
    int idx = blockIdx.x * 256 + threadIdx.x;
    if (idx < 8192) {                      // A1 (c1): frag (o2, ks, lane); A-row m = k2
        int o2 = idx >> 9, ks = (idx >> 6) & 7, l = idx & 63;
        int k2 = l & 15;
        unsigned short* dst = ws + ((size_t)(o2 * 8 + ks) * 64 + l) * 8;
        #pragma unroll
        for (int j = 0; j < 8; ++j) {
            int k = ks * 32 + ((l >> 4) * 8) + j;      // kappa = (i2,k1)
            dst[j] = f2bf(c1[(k & 15) * 4096 + o2 * 256 + (k >> 4) * 16 + k2]);
        }
    } else if (idx < 9216) {               // A0 (c0): frag (o1, lane); A-row m = k1; K=16 pad
        int t = idx - 8192;
        int o1 = t >> 6, l = t & 63;
        unsigned short* dst = ws + WS_A0_OFF / 2 + ((size_t)o1 * 64 + l) * 8;
        #pragma unroll
        for (int j = 0; j < 8; ++j) {
            int k = ((l >> 4) * 8) + j;                // i1 (or pad)
            float v = (l < 32) ? c0[o1 * 256 + k * 16 + (l & 15)] : 0.f;
            dst[j] = f2bf(v);
        }
    } else if (idx < 9728) {               // A2 (c2): frag (ks, lane); A-row m = o3
        int t = idx - 9216;
        int ks = t >> 6, l = t & 63;
        unsigned short* dst = ws + WS_A2_OFF / 2 + ((size_t)ks * 64 + l) * 8;
        #pragma unroll
        for (int j = 0; j < 8; ++j) {
            int k = ks * 32 + ((l >> 4) * 8) + j;      // kappa2 = (i3,k2)
            dst[j] = f2bf(c2[(k & 15) * 256 + (l & 15) * 16 + (k >> 4)]);
        }
    }
}

// ---------------- main kernel ----------------
template <bool PACKED>
__global__ __launch_bounds__(256, 2) void tt_main(
    const float* __restrict__ vg, const float* __restrict__ c0,
    const float* __restrict__ c1, const float* __restrict__ c2,
    const unsigned short* __restrict__ ws, float* __restrict__ outg)
{
    __shared__ unsigned short T1[16384]; // [n=(o1l,i3) 64][k=(i2,k1) 256], byte ^ ((n&7)<<4)
    __shared__ unsigned short T2[16384]; // [n=(o1l,o2) 64][k=(i3,k2) 256], byte ^ ((n&7)<<4)

    const int b   = blockIdx.x;
    const int t   = threadIdx.x;
    const int w   = t >> 6;        // wave 0..3
    const int l   = t & 63;
    const int l15 = l & 15;
    const int lg  = l >> 4;

    // ---- preload: v B-frags (per-b) and c2 A-frags (small, held: 32 VGPR) ----
    bf16x8 fb0[4];
    {
        const float* vb = vg + (size_t)b * 4096;
        #pragma unroll
        for (int nt = 0; nt < 4; ++nt) {
            bf16x8 f = {0, 0, 0, 0, 0, 0, 0, 0};
            if (l < 32) {
                int i2 = 4 * w + nt;
                const float* p = vb + (lg * 8) * 256 + i2 * 16 + l15;
                #pragma unroll
                for (int j = 0; j < 8; ++j) f[j] = (short)f2bf(p[j * 256]);
            }
            fb0[nt] = f;
        }
    }
    bf16x8 fa2[8];
    if constexpr (PACKED) {
        #pragma unroll
        for (int ks = 0; ks < 8; ++ks)
            fa2[ks] = *(const bf16x8*)(ws + WS_A2_OFF / 2 + ((size_t)ks * 64 + l) * 8);
    } else {
        for (int ks = 0; ks < 8; ++ks) {
            bf16x8 f;
            for (int j = 0; j < 8; ++j) {
                int k = ks * 32 + lg * 8 + j;
                f[j] = (short)f2bf(c2[(k & 15) * 256 + l15 * 16 + (k >> 4)]);
            }
            fa2[ks] = f;
        }
    }

    // per-thread base into the c1 frag table: frag(o2=4w+rt, ks) at +(rt*8+ks)*512 shorts
    const unsigned short* a1p = PACKED ? (ws + (size_t)l * 8 + (size_t)w * 32 * 512) : nullptr;

    for (int nc = 0; nc < 4; ++nc) {       // o1 chunk: o1 = nc*4 .. nc*4+3
        // ---------- S1: T1 rows (o1l,i3), k=(i2,k1) ----------
        #pragma unroll
        for (int mtl = 0; mtl < 4; ++mtl) {
            const int o1 = nc * 4 + mtl;
            bf16x8 fa0;
            if constexpr (PACKED) {
                fa0 = *(const bf16x8*)(ws + WS_A0_OFF / 2 + ((size_t)o1 * 64 + l) * 8);
            } else {
                bf16x8 f = {0, 0, 0, 0, 0, 0, 0, 0};
                if (l < 32) {
                    #pragma unroll
                    for (int j = 0; j < 8; ++j)
                        f[j] = (short)f2bf(c0[o1 * 256 + (lg * 8 + j) * 16 + l15]);
                }
                fa0 = f;
            }
            #pragma unroll
            for (int nt = 0; nt < 4; ++nt) {
                f32x4 z = {0.f, 0.f, 0.f, 0.f};
                f32x4 d = __builtin_amdgcn_mfma_f32_16x16x32_bf16(fa0, fb0[nt], z, 0, 0, 0);
                // D: row=k1=lg*4+r, col=i3=l15; this tile: i2 = 4w+nt
                const int i2 = 4 * w + nt;
                const int n  = mtl * 16 + l15;
                int byte = (n * 512 + (i2 * 16 + lg * 4) * 2) ^ ((l15 & 7) << 4);
                uint2 wv;
                wv.x = pk_bf16(d[0], d[1]);
                wv.y = pk_bf16(d[2], d[3]);
                *(uint2*)((char*)T1 + byte) = wv;   // 4 consecutive k1 -> one b64
            }
        }
        __syncthreads();

        // ---------- S2: T2 = c1m x T1; wave w owns o2 = 4w..4w+3 ----------
        {
            f32x4 acc[4][4];
            #pragma unroll
            for (int rt = 0; rt < 4; ++rt)
                #pragma unroll
                for (int nt = 0; nt < 4; ++nt) acc[rt][nt] = (f32x4){0.f, 0.f, 0.f, 0.f};

            #pragma unroll 2
            for (int ks = 0; ks < 8; ++ks) {
                bf16x8 fa_0, fa_1, fa_2, fa_3;   // streamed from L2 (NOT held: spills)
                if constexpr (PACKED) {
                    fa_0 = *(const bf16x8*)(a1p + (0 * 8 + ks) * 512);
                    fa_1 = *(const bf16x8*)(a1p + (1 * 8 + ks) * 512);
                    fa_2 = *(const bf16x8*)(a1p + (2 * 8 + ks) * 512);
                    fa_3 = *(const bf16x8*)(a1p + (3 * 8 + ks) * 512);
                } else {
                    bf16x8 ftmp[4];
                    for (int rt = 0; rt < 4; ++rt) {
                        int o2 = w * 4 + rt;
                        bf16x8 f;
                        for (int j = 0; j < 8; ++j) {
                            int k = ks * 32 + lg * 8 + j;
                            f[j] = (short)f2bf(c1[(k & 15) * 4096 + o2 * 256 + (k >> 4) * 16 + l15]);
                        }
                        ftmp[rt] = f;
                    }
                    fa_0 = ftmp[0]; fa_1 = ftmp[1]; fa_2 = ftmp[2]; fa_3 = ftmp[3];
                }
                #pragma unroll
                for (int nt = 0; nt < 4; ++nt) {
                    int byte = ((nt * 16 + l15) * 512 + (ks * 32 + lg * 8) * 2) ^ ((l15 & 7) << 4);
                    bf16x8 fb = *(const bf16x8*)((char*)T1 + byte);
                    acc[0][nt] = __builtin_amdgcn_mfma_f32_16x16x32_bf16(fa_0, fb, acc[0][nt], 0, 0, 0);
                    acc[1][nt] = __builtin_amdgcn_mfma_f32_16x16x32_bf16(fa_1, fb, acc[1][nt], 0, 0, 0);
                    acc[2][nt] = __builtin_amdgcn_mfma_f32_16x16x32_bf16(fa_2, fb, acc[2][nt], 0, 0, 0);
                    acc[3][nt] = __builtin_amdgcn_mfma_f32_16x16x32_bf16(fa_3, fb, acc[3][nt], 0, 0, 0);
                }
            }
            // flush: D row=k2=lg*4+r, col=(o1l=nt, i3=l15); T2 k=(i3,k2) -> r consecutive
            #pragma unroll
            for (int rt = 0; rt < 4; ++rt) {
                const int o2 = w * 4 + rt;
                #pragma unroll
                for (int nt = 0; nt < 4; ++nt) {
                    int byte = ((nt * 16 + o2) * 512 + (l15 * 16 + lg * 4) * 2) ^ ((o2 & 7) << 4);
                    uint2 wv;
                    wv.x = pk_bf16(acc[rt][nt][0], acc[rt][nt][1]);
                    wv.y = pk_bf16(acc[rt][nt][2], acc[rt][nt][3]);
                    *(uint2*)((char*)T2 + byte) = wv;
                }
            }
        }
        __syncthreads();

        // ---------- S3: wave w owns o1l = w (no cross-wave duplication) ----------
        {
            f32x4 acc3 = {0.f, 0.f, 0.f, 0.f};
            #pragma unroll
            for (int ks = 0; ks < 8; ++ks) {
                int byte = ((w * 16 + l15) * 512 + (ks * 32 + lg * 8) * 2) ^ ((l15 & 7) << 4);
                bf16x8 fb = *(const bf16x8*)((char*)T2 + byte);  // n=o2=l15, k=(i3,k2)
                acc3 = __builtin_amdgcn_mfma_f32_16x16x32_bf16(fa2[ks], fb, acc3, 0, 0, 0);
            }
            // D: row=o3=lg*4+r, col=o2=l15
            float* ob = outg + (size_t)b * 4096;
            *(f32x4*)(ob + (nc * 4 + w) * 256 + l15 * 16 + lg * 4) = acc3;
        }
        __syncthreads();
    }
}

extern "C" void kernel_launch(void* const* d_in, const int* in_sizes, int n_in,
                              void* d_out, int out_size, void* d_ws, size_t ws_size,
                              hipStream_t stream) {
    const float* vg  = (const float*)d_in[0];
    const float* c0g = (const float*)d_in[1];
    const float* c1g = (const float*)d_in[2];
    const float* c2g = (const float*)d_in[3];
    float* outg = (float*)d_out;

    const int B = in_sizes[0] / 4096;
    const bool packed = (ws_size >= (size_t)WS_NEEDED) && (d_ws != nullptr);

    if (packed) {
        tt_repack<<<dim3(38), dim3(256), 0, stream>>>(c0g, c1g, c2g, (unsigned short*)d_ws);
        tt_main<true><<<dim3(B), dim3(256), 0, stream>>>(
            vg, c0g, c1g, c2g, (const unsigned short*)d_ws, outg);
    } else {
        tt_main<false><<<dim3(B), dim3(256), 0, stream>>>(
            vg, c0g, c1g, c2g, nullptr, outg);
    }
}

// Round 5
// 53.984 us; speedup vs baseline: 20.1109x; 1.0057x over previous
//
#include <hip/hip_runtime.h>
#include <hip/hip_bf16.h>

// TT/MPO matvec on MFMA (bf16 in / f32 accum), round 5.
//   S1: T1[(o1l,i3)][(i2,k1)] = c0m x v        (per o1, K=16 pad 32)
//   S2: T2[(o1l,o2)][(i3,k2)] = c1m x T1       (M tiled by o2, K=(i2,k1))
//   S3: out[b,o1,o2,o3]       = c2m x T2       (wave w<4 owns o1l=w)
// Block = one b, 8 waves (512 thr), o1 chunked by 4. LDS 64 KB -> 2 blocks/CU
// = 16 waves/CU (round-4 lesson: 4-wave blocks gave 18% occupancy, latency-bound).
// c1 A-frags STREAMED from L2-resident ws (round-2 lesson: holding spills).
// Pack via __float22bfloat162_rn (round-3 lesson: raw v_cvt_pk asm NaN'd;
// round-4 software f2bf pack ~10 VALU -> library intrinsic).

typedef short bf16x8 __attribute__((ext_vector_type(8)));
typedef float f32x4 __attribute__((ext_vector_type(4)));

#define WS_A1_OFF 0        // c1 frags: 16 o2 x 8 ks x 64 lanes x 16B = 131072 B
#define WS_A0_OFF 131072   // c0 frags: 16 o1 x 64 lanes x 16B       = 16384 B
#define WS_A2_OFF 147456   // c2 frags:  8 ks x 64 lanes x 16B       = 8192 B
#define WS_NEEDED 155648

__device__ __forceinline__ unsigned short f2bf(float f) {
    union { float f; unsigned int u; } x; x.f = f;
    unsigned int u = x.u;
    u += 0x7fffu + ((u >> 16) & 1u);   // RNE
    return (unsigned short)(u >> 16);
}

__device__ __forceinline__ unsigned int pk_bf16(float lo, float hi) {
    __hip_bfloat162 h = __float22bfloat162_rn(make_float2(lo, hi));  // RNE, x=lo -> [15:0]
    unsigned int r;
    __builtin_memcpy(&r, &h, 4);
    return r;
}

// ---------------- repack: c0/c1/c2 -> bf16 A-fragment layout in ws ----------------
// k-dim orderings: S2 kappa=(i2,k1): i2=k>>4, k1=k&15.  S3 kappa2=(i3,k2): i3=k>>4, k2=k&15.
__global__ void tt_repack(const float* __restrict__ c0,
                          const float* __restrict__ c1,
                          const float* __restrict__ c2,
                          unsigned short* __restrict__ ws) {
    int idx = blockIdx.x * 256 + threadIdx.x;
    if (idx < 8192) {                      // A1 (c1): frag (o2, ks, lane); A-row m = k2
        int o2 = idx >> 9, ks = (idx >> 6) & 7, l = idx & 63;
        int k2 = l & 15;
        unsigned short* dst = ws + ((size_t)(o2 * 8 + ks) * 64 + l) * 8;
        #pragma unroll
        for (int j = 0; j < 8; ++j) {
            int k = ks * 32 + ((l >> 4) * 8) + j;      // kappa = (i2,k1)
            dst[j] = f2bf(c1[(k & 15) * 4096 + o2 * 256 + (k >> 4) * 16 + k2]);
        }
    } else if (idx < 9216) {               // A0 (c0): frag (o1, lane); A-row m = k1; K=16 pad
        int t = idx - 8192;
        int o1 = t >> 6, l = t & 63;
        unsigned short* dst = ws + WS_A0_OFF / 2 + ((size_t)o1 * 64 + l) * 8;
        #pragma unroll
        for (int j = 0; j < 8; ++j) {
            int k = ((l >> 4) * 8) + j;                // i1 (or pad)
            float v = (l < 32) ? c0[o1 * 256 + k * 16 + (l & 15)] : 0.f;
            dst[j] = f2bf(v);
        }
    } else if (idx < 9728) {               // A2 (c2): frag (ks, lane); A-row m = o3
        int t = idx - 9216;
        int ks = t >> 6, l = t & 63;
        unsigned short* dst = ws + WS_A2_OFF / 2 + ((size_t)ks * 64 + l) * 8;
        #pragma unroll
        for (int j = 0; j < 8; ++j) {
            int k = ks * 32 + ((l >> 4) * 8) + j;      // kappa2 = (i3,k2)
            dst[j] = f2bf(c2[(k & 15) * 256 + (l & 15) * 16 + (k >> 4)]);
        }
    }
}

// ---------------- main kernel: 512 threads = 8 waves ----------------
template <bool PACKED>
__global__ __launch_bounds__(512, 4) void tt_main(
    const float* __restrict__ vg, const float* __restrict__ c0,
    const float* __restrict__ c1, const float* __restrict__ c2,
    const unsigned short* __restrict__ ws, float* __restrict__ outg)
{
    __shared__ unsigned short T1[16384]; // [n=(o1l,i3) 64][k=(i2,k1) 256], byte ^ ((n&7)<<4)
    __shared__ unsigned short T2[16384]; // [n=(o1l,o2) 64][k=(i3,k2) 256], byte ^ ((n&7)<<4)

    const int b   = blockIdx.x;
    const int t   = threadIdx.x;
    const int w   = t >> 6;        // wave 0..7
    const int l   = t & 63;
    const int l15 = l & 15;
    const int lg  = l >> 4;

    // ---- preload: v B-frags (this wave's 2 i2 values) and c2 A-frags ----
    bf16x8 fb0[2];
    {
        const float* vb = vg + (size_t)b * 4096;
        #pragma unroll
        for (int nt = 0; nt < 2; ++nt) {
            bf16x8 f = {0, 0, 0, 0, 0, 0, 0, 0};
            if (l < 32) {
                int i2 = 2 * w + nt;
                const float* p = vb + (lg * 8) * 256 + i2 * 16 + l15;
                #pragma unroll
                for (int j = 0; j < 8; ++j) f[j] = (short)f2bf(p[j * 256]);
            }
            fb0[nt] = f;
        }
    }
    bf16x8 fa2[8];
    if constexpr (PACKED) {
        #pragma unroll
        for (int ks = 0; ks < 8; ++ks)
            fa2[ks] = *(const bf16x8*)(ws + WS_A2_OFF / 2 + ((size_t)ks * 64 + l) * 8);
    } else {
        for (int ks = 0; ks < 8; ++ks) {
            bf16x8 f;
            for (int j = 0; j < 8; ++j) {
                int k = ks * 32 + lg * 8 + j;
                f[j] = (short)f2bf(c2[(k & 15) * 256 + l15 * 16 + (k >> 4)]);
            }
            fa2[ks] = f;
        }
    }

    // per-thread lane slot in the c1 frag table; frag (o2,ks) at +(o2*8+ks)*512 shorts
    const unsigned short* a1p = PACKED ? (ws + (size_t)l * 8) : nullptr;

    for (int nc = 0; nc < 4; ++nc) {       // o1 chunk: o1 = nc*4 .. nc*4+3
        // ---------- S1: T1 rows (o1l,i3), k=(i2,k1); wave covers i2 = 2w,2w+1 ----------
        #pragma unroll
        for (int mtl = 0; mtl < 4; ++mtl) {
            const int o1 = nc * 4 + mtl;
            bf16x8 fa0;
            if constexpr (PACKED) {
                fa0 = *(const bf16x8*)(ws + WS_A0_OFF / 2 + ((size_t)o1 * 64 + l) * 8);
            } else {
                bf16x8 f = {0, 0, 0, 0, 0, 0, 0, 0};
                if (l < 32) {
                    #pragma unroll
                    for (int j = 0; j < 8; ++j)
                        f[j] = (short)f2bf(c0[o1 * 256 + (lg * 8 + j) * 16 + l15]);
                }
                fa0 = f;
            }
            #pragma unroll
            for (int nt = 0; nt < 2; ++nt) {
                f32x4 z = {0.f, 0.f, 0.f, 0.f};
                f32x4 d = __builtin_amdgcn_mfma_f32_16x16x32_bf16(fa0, fb0[nt], z, 0, 0, 0);
                // D: row=k1=lg*4+r, col=i3=l15; this tile: i2 = 2w+nt
                const int i2 = 2 * w + nt;
                const int n  = mtl * 16 + l15;
                int byte = (n * 512 + (i2 * 16 + lg * 4) * 2) ^ ((l15 & 7) << 4);
                uint2 wv;
                wv.x = pk_bf16(d[0], d[1]);
                wv.y = pk_bf16(d[2], d[3]);
                *(uint2*)((char*)T1 + byte) = wv;   // 4 consecutive k1 -> one b64
            }
        }
        __syncthreads();

        // ---------- S2: T2 = c1m x T1; wave w owns o2 = 2w, 2w+1 ----------
        {
            f32x4 acc[2][4];
            #pragma unroll
            for (int rt = 0; rt < 2; ++rt)
                #pragma unroll
                for (int nt = 0; nt < 4; ++nt) acc[rt][nt] = (f32x4){0.f, 0.f, 0.f, 0.f};

            #pragma unroll 2
            for (int ks = 0; ks < 8; ++ks) {
                bf16x8 fa_0, fa_1;   // streamed from L2 (NOT held: spills)
                if constexpr (PACKED) {
                    fa_0 = *(const bf16x8*)(a1p + ((2 * w + 0) * 8 + ks) * 512);
                    fa_1 = *(const bf16x8*)(a1p + ((2 * w + 1) * 8 + ks) * 512);
                } else {
                    bf16x8 ftmp[2];
                    for (int rt = 0; rt < 2; ++rt) {
                        int o2 = 2 * w + rt;
                        bf16x8 f;
                        for (int j = 0; j < 8; ++j) {
                            int k = ks * 32 + lg * 8 + j;
                            f[j] = (short)f2bf(c1[(k & 15) * 4096 + o2 * 256 + (k >> 4) * 16 + l15]);
                        }
                        ftmp[rt] = f;
                    }
                    fa_0 = ftmp[0]; fa_1 = ftmp[1];
                }
                #pragma unroll
                for (int nt = 0; nt < 4; ++nt) {
                    int byte = ((nt * 16 + l15) * 512 + (ks * 32 + lg * 8) * 2) ^ ((l15 & 7) << 4);
                    bf16x8 fb = *(const bf16x8*)((char*)T1 + byte);
                    acc[0][nt] = __builtin_amdgcn_mfma_f32_16x16x32_bf16(fa_0, fb, acc[0][nt], 0, 0, 0);
                    acc[1][nt] = __builtin_amdgcn_mfma_f32_16x16x32_bf16(fa_1, fb, acc[1][nt], 0, 0, 0);
                }
            }
            // flush: D row=k2=lg*4+r, col=(o1l=nt, i3=l15); T2 k=(i3,k2) -> r consecutive
            #pragma unroll
            for (int rt = 0; rt < 2; ++rt) {
                const int o2 = 2 * w + rt;
                #pragma unroll
                for (int nt = 0; nt < 4; ++nt) {
                    int byte = ((nt * 16 + o2) * 512 + (l15 * 16 + lg * 4) * 2) ^ ((o2 & 7) << 4);
                    uint2 wv;
                    wv.x = pk_bf16(acc[rt][nt][0], acc[rt][nt][1]);
                    wv.y = pk_bf16(acc[rt][nt][2], acc[rt][nt][3]);
                    *(uint2*)((char*)T2 + byte) = wv;
                }
            }
        }
        __syncthreads();

        // ---------- S3: waves 0..3 own o1l = w ----------
        if (w < 4) {
            f32x4 acc3 = {0.f, 0.f, 0.f, 0.f};
            #pragma unroll
            for (int ks = 0; ks < 8; ++ks) {
                int byte = ((w * 16 + l15) * 512 + (ks * 32 + lg * 8) * 2) ^ ((l15 & 7) << 4);
                bf16x8 fb = *(const bf16x8*)((char*)T2 + byte);  // n=o2=l15, k=(i3,k2)
                acc3 = __builtin_amdgcn_mfma_f32_16x16x32_bf16(fa2[ks], fb, acc3, 0, 0, 0);
            }
            // D: row=o3=lg*4+r, col=o2=l15
            float* ob = outg + (size_t)b * 4096;
            *(f32x4*)(ob + (nc * 4 + w) * 256 + l15 * 16 + lg * 4) = acc3;
        }
        __syncthreads();
    }
}

extern "C" void kernel_launch(void* const* d_in, const int* in_sizes, int n_in,
                              void* d_out, int out_size, void* d_ws, size_t ws_size,
                              hipStream_t stream) {
    const float* vg  = (const float*)d_in[0];
    const float* c0g = (const float*)d_in[1];
    const float* c1g = (const float*)d_in[2];
    const float* c2g = (const float*)d_in[3];
    float* outg = (float*)d_out;

    const int B = in_sizes[0] / 4096;
    const bool packed = (ws_size >= (size_t)WS_NEEDED) && (d_ws != nullptr);

    if (packed) {
        tt_repack<<<dim3(38), dim3(256), 0, stream>>>(c0g, c1g, c2g, (unsigned short*)d_ws);
        tt_main<true><<<dim3(B), dim3(512), 0, stream>>>(
            vg, c0g, c1g, c2g, (const unsigned short*)d_ws, outg);
    } else {
        tt_main<false><<<dim3(B), dim3(512), 0, stream>>>(
            vg, c0g, c1g, c2g, nullptr, outg);
    }
}